// Round 3
// baseline (889.628 us; speedup 1.0000x reference)
//
#include <hip/hip_runtime.h>
#include <math.h>

#define N_NODES 100000
#define N_EDGES 3200000
#define F_IN    512
#define F1      16
#define F2      40

// graph-build radix: 196 coarse buckets of 512 nodes (c>>9)
#define NB1    196
#define BDEPTH 32        // LDS buffer depth per bucket (2 lines)
#define CAP1   21536     // staging1 capacity/bucket: 16327 mean + pads(512WG*7.5=3840) + 8 sigma; x16 aligned
#define CAPR   17664     // rows_sorted window/bucket: 16327 mean + 10 sigma; fixed stride (no scan needed)
#define NWG1   512       // bin workgroups; chunk = 3.2M/512 = 6250 exactly
#define STASH  4096      // overflow stash entries (expected use: 0)

// mm1 tiling
#define BR 256
#define KK 32
#define XPITCH 36

__device__ __forceinline__ int xcc_id() {
    unsigned x;
    asm volatile("s_getreg_b32 %0, hwreg(HW_REG_XCC_ID)" : "=s"(x));
    return (int)(x & 7);
}

// ------- layer-1 matmul, LDS-tiled: h1t[r] = dis[r]*(x[r]@W1 + b1) -------
__global__ __launch_bounds__(256, 4) void mm1_kernel(
        const float* __restrict__ x, const float* __restrict__ W1,
        const float* __restrict__ b1, const float* __restrict__ dis,
        float* __restrict__ h1t) {
    __shared__ float xs[BR * XPITCH];
    __shared__ float ws[KK * F1];
    int t = threadIdx.x;
    int rbase = blockIdx.x * BR;
    int jq = t & 3;
    int rg = t >> 2;
    float acc[4][4];
#pragma unroll
    for (int i = 0; i < 4; ++i)
#pragma unroll
        for (int j = 0; j < 4; ++j) acc[i][j] = 0.0f;

    for (int ch = 0; ch < F_IN / KK; ++ch) {
        int c0 = ch * KK;
#pragma unroll
        for (int i = 0; i < 8; ++i) {
            int p  = t + i * 256;
            int tr = p >> 3;
            int f4 = p & 7;
            float4 v = make_float4(0.0f, 0.0f, 0.0f, 0.0f);
            int grow = rbase + tr;
            if (grow < N_NODES)
                v = *(const float4*)(x + (size_t)grow * F_IN + c0 + f4 * 4);
            *(float4*)&xs[tr * XPITCH + f4 * 4] = v;
        }
        if (t < 128) {
            int kk = t >> 2, f4 = t & 3;
            *(float4*)&ws[kk * F1 + f4 * 4] =
                *(const float4*)(W1 + (size_t)(c0 + kk) * F1 + f4 * 4);
        }
        __syncthreads();
#pragma unroll
        for (int k4 = 0; k4 < KK / 4; ++k4) {
            float xa[4][4], wa[4][4];
#pragma unroll
            for (int i = 0; i < 4; ++i)
                *(float4*)&xa[i][0] =
                    *(const float4*)&xs[(rg * 4 + i) * XPITCH + k4 * 4];
#pragma unroll
            for (int m = 0; m < 4; ++m)
                *(float4*)&wa[m][0] =
                    *(const float4*)&ws[(k4 * 4 + m) * F1 + jq * 4];
#pragma unroll
            for (int i = 0; i < 4; ++i)
#pragma unroll
                for (int m = 0; m < 4; ++m)
#pragma unroll
                    for (int j = 0; j < 4; ++j)
                        acc[i][j] = fmaf(xa[i][m], wa[m][j], acc[i][j]);
        }
        __syncthreads();
    }

    float4 bv = *(const float4*)(b1 + jq * 4);
#pragma unroll
    for (int i = 0; i < 4; ++i) {
        int grow = rbase + rg * 4 + i;
        if (grow < N_NODES) {
            float d = dis[grow];
            float4 o;
            o.x = d * (acc[i][0] + bv.x);
            o.y = d * (acc[i][1] + bv.y);
            o.z = d * (acc[i][2] + bv.z);
            o.w = d * (acc[i][3] + bv.w);
            *(float4*)(h1t + (size_t)grow * F1 + jq * 4) = o;
        }
    }
}

// ---------------- init: zero deg8 + cursors ------------------------------
__global__ void init_kernel(int* __restrict__ deg8, int* __restrict__ gcur1,
                            int* __restrict__ oscur) {
    int i = blockIdx.x * blockDim.x + threadIdx.x;
    if (i < 8 * 102400) deg8[i] = 0;
    if (i < NB1) gcur1[i] = 0;
    if (i == 0) *oscur = 0;
}

// ---- bin: LDS line-buffered radix to 196 coarse buckets. Every global
// staging write is a FULL aligned 64B line (4 lanes x int4 cooperative
// flush), because scattered sub-line stores on this part cost one masked
// 64B fabric/HBM write EACH (R0-R2 counters: WRITE_SIZE == 68B/edge,
// invariant under XCD ownership). Remainders padded with -1 sentinels.
__global__ __launch_bounds__(256) void bin_kernel(
        const int* __restrict__ row, const int* __restrict__ col,
        int* __restrict__ deg8, int* __restrict__ gcur1, int* __restrict__ oscur,
        int2* __restrict__ stash, int* __restrict__ staging1) {
    __shared__ int buf1[NB1][BDEPTH];
    __shared__ int cur1[NB1];
    __shared__ int myBase[NB1];
    __shared__ short flushList[2 * NB1];
    __shared__ int flushCnt;
    int t = threadIdx.x;
    int part = xcc_id();
    for (int i = t; i < NB1; i += 256) cur1[i] = 0;
    if (t == 0) flushCnt = 0;
    __syncthreads();
    const int chunk = N_EDGES / NWG1;          // 6250
    int e0 = blockIdx.x * chunk;
    const int nbatch = (chunk + 255) / 256;    // 25
    for (int batch = 0; batch <= nbatch; ++batch) {
        if (batch < nbatch) {
            int e = e0 + batch * 256 + t;
            if (e < e0 + chunk) {
                int r = row[e];
                int c = col[e];
                atomicAdd(&deg8[part * 102400 + r], 1);   // fire-and-forget
                int p1 = r | ((c & 511) << 17);
                int bb = c >> 9;
                int pos = atomicAdd(&cur1[bb], 1);
                if (pos < BDEPTH) buf1[bb][pos] = p1;
                else { int sp = atomicAdd(oscur, 1);      // statistically never
                       if (sp < STASH) stash[sp] = make_int2(bb, p1); }
            }
        } else {
            // drain: pad remainder up to a full 16-entry line with sentinels
            if (t < NB1) {
                int rem = min(cur1[t], BDEPTH);
                if (rem & 15) {
                    int up = (rem + 15) & ~15;
                    for (int i = rem; i < up; ++i) buf1[t][i] = -1;
                    cur1[t] = up;
                }
            }
        }
        __syncthreads();
        // reserve windows for full lines
        if (t < NB1) {
            int n = min(cur1[t], BDEPTH);
            int lines = n >> 4;
            if (lines) {
                int base = atomicAdd(&gcur1[t], lines * 16);
                if (base + lines * 16 <= CAP1) {
                    myBase[t] = base;
                    int li = atomicAdd(&flushCnt, lines);
                    for (int L = 0; L < lines; ++L)
                        flushList[li + L] = (short)((t << 2) | L);
                } else {                                   // statistically never
                    for (int i = 0; i < lines * 16; ++i) {
                        int sp = atomicAdd(oscur, 1);
                        if (sp < STASH) stash[sp] = make_int2(t, buf1[t][i]);
                    }
                }
            }
        }
        __syncthreads();
        // cooperative full-line copy: 4 lanes x int4 per line
        int fc = flushCnt;
        for (int j = t; j < fc * 4; j += 256) {
            int g = flushList[j >> 2];
            int lane4 = j & 3;
            int bb = g >> 2, L = g & 3;
            int4 v = *(int4*)&buf1[bb][L * 16 + lane4 * 4];
            *(int4*)&staging1[(size_t)bb * CAP1 + myBase[bb] + L * 16 + lane4 * 4] = v;
        }
        __syncthreads();
        // compact remainders, reset list
        if (t < NB1) {
            int n = min(cur1[t], BDEPTH);
            int lines = n >> 4, rem = n & 15;
            if (lines) for (int i = 0; i < rem; ++i) buf1[t][i] = buf1[t][lines * 16 + i];
            cur1[t] = rem;
        }
        if (t == 0) flushCnt = 0;
        __syncthreads();
    }
}

// ---- dis = (deg+1)^-0.5 (+1 self loop); deg = sum of 8 per-XCD copies ---
__global__ void dis_kernel(const int* __restrict__ deg8, float* __restrict__ dis) {
    int i = blockIdx.x * blockDim.x + threadIdx.x;
    if (i < N_NODES) {
        int d = 1;
#pragma unroll
        for (int p = 0; p < 8; ++p) d += deg8[p * 102400 + i];
        dis[i] = rsqrtf((float)d);
    }
}

// ---- csr2: per coarse bucket, sort ~16K entries fully in LDS (512-counter
// histogram -> scan -> LDS scatter), then stream rows_sorted out COALESCED.
// Fixed per-bucket stride CAPR -> no global scan. Replaces csr+scanb and
// eliminates their 3.2M scattered 4B global writes.
__global__ __launch_bounds__(256) void csr2_kernel(
        const int* __restrict__ staging1, const int* __restrict__ gcur1,
        const int* __restrict__ oscur, const int2* __restrict__ stash,
        int* __restrict__ start, int* __restrict__ cnt,
        int* __restrict__ rows_sorted) {
    __shared__ int ebuf[CAPR];
    __shared__ int cnt512[512], off512[512], cur512[512];
    __shared__ int psum[256];
    int b = blockIdx.x, t = threadIdx.x;
    for (int i = t; i < 512; i += 256) { cnt512[i] = 0; cur512[i] = 0; }
    __syncthreads();
    const int* sb = staging1 + (size_t)b * CAP1;
    int n1 = min(gcur1[b], CAP1);
    for (int k = t; k < n1; k += 256) {
        int e = sb[k];
        if (e != -1) atomicAdd(&cnt512[(e >> 17) & 511], 1);
    }
    int ns = min(*oscur, STASH);
    for (int k = t; k < ns; k += 256) {
        int2 se = stash[k];
        if (se.x == b && se.y != -1) atomicAdd(&cnt512[(se.y >> 17) & 511], 1);
    }
    __syncthreads();
    // exclusive scan of 512 counters: pair-sum -> 256-wide Hillis-Steele
    int a0 = cnt512[2 * t], a1 = cnt512[2 * t + 1];
    int ps = a0 + a1;
    psum[t] = ps;
    __syncthreads();
    for (int off = 1; off < 256; off <<= 1) {
        int v = (t >= off) ? psum[t - off] : 0;
        __syncthreads();
        psum[t] += v;
        __syncthreads();
    }
    int excl = psum[t] - ps;
    off512[2 * t] = excl;
    off512[2 * t + 1] = excl + a0;
    __syncthreads();
    for (int i = t; i < 512; i += 256) {
        int node = b * 512 + i;                    // max 100351 < 102400
        start[node] = b * CAPR + off512[i];
        cnt[node]   = cnt512[i];
    }
    // scatter into LDS
    for (int k = t; k < n1; k += 256) {
        int e = sb[k];
        if (e != -1) {
            int i = (e >> 17) & 511;
            int pos = atomicAdd(&cur512[i], 1);
            int dst = off512[i] + pos;
            if (dst < CAPR) ebuf[dst] = e & 0x1FFFF;
        }
    }
    for (int k = t; k < ns; k += 256) {
        int2 se = stash[k];
        if (se.x == b && se.y != -1) {
            int i = (se.y >> 17) & 511;
            int pos = atomicAdd(&cur512[i], 1);
            int dst = off512[i] + pos;
            if (dst < CAPR) ebuf[dst] = se.y & 0x1FFFF;
        }
    }
    __syncthreads();
    int total = off512[511] + cnt512[511];
    if (total > CAPR) total = CAPR;
    int* out = rows_sorted + (size_t)b * CAPR;
    for (int k = t; k < total; k += 256) out[k] = ebuf[k];   // coalesced full lines
}

// ------- layer-1 aggregation (dis-folded) + relu + row-sum s -------------
__global__ void agg1_kernel(const int* __restrict__ rows_sorted,
                            const int* __restrict__ start, const int* __restrict__ cnt,
                            const float* __restrict__ dis, const float* __restrict__ h1t,
                            float* __restrict__ g, float* __restrict__ s_out) {
    int idx = blockIdx.x * blockDim.x + threadIdx.x;
    if (idx >= N_NODES * 4) return;
    int c = idx >> 2;
    int q = idx & 3;
    float dc = dis[c];
    const float4* h4 = (const float4*)h1t;
    float4 acc = h4[(size_t)c * 4 + q];
    float ss = dc;
    int k0 = start[c];
    int k1 = k0 + cnt[c];
    for (int k = k0; k < k1; ++k) {
        int r = rows_sorted[k];
        float4 v = h4[(size_t)r * 4 + q];
        acc.x += v.x; acc.y += v.y; acc.z += v.z; acc.w += v.w;
        if (q == 0) ss += dis[r];
    }
    acc.x = dc * fmaxf(acc.x * dc, 0.0f);
    acc.y = dc * fmaxf(acc.y * dc, 0.0f);
    acc.z = dc * fmaxf(acc.z * dc, 0.0f);
    acc.w = dc * fmaxf(acc.w * dc, 0.0f);
    ((float4*)g)[(size_t)c * 4 + q] = acc;
    if (q == 0) s_out[c] = dc * ss;
}

// ---------------- layer-2 aggregation (dis-folded): t = A_hat g ----------
__global__ void agg2_kernel(const int* __restrict__ rows_sorted,
                            const int* __restrict__ start, const int* __restrict__ cnt,
                            const float* __restrict__ dis, const float* __restrict__ g,
                            float* __restrict__ t) {
    int idx = blockIdx.x * blockDim.x + threadIdx.x;
    if (idx >= N_NODES * 4) return;
    int c = idx >> 2;
    int q = idx & 3;
    float dc = dis[c];
    const float4* h4 = (const float4*)g;
    float4 acc = h4[(size_t)c * 4 + q];
    int k0 = start[c];
    int k1 = k0 + cnt[c];
    for (int k = k0; k < k1; ++k) {
        int r = rows_sorted[k];
        float4 v = h4[(size_t)r * 4 + q];
        acc.x += v.x; acc.y += v.y; acc.z += v.z; acc.w += v.w;
    }
    acc.x *= dc; acc.y *= dc; acc.z *= dc; acc.w *= dc;
    ((float4*)t)[(size_t)c * 4 + q] = acc;
}

// ------- fused: out = log_softmax(t @ W2 + s*b2^T), wave per node ---------
__global__ void mm2lsm_kernel(const float* __restrict__ t, const float* __restrict__ s,
                              const float* __restrict__ W2, const float* __restrict__ b2,
                              float* __restrict__ out) {
    __shared__ float w2s[F1 * F2];
    __shared__ float b2s[F2];
    __shared__ float ts[4 * F1];
    int tid = threadIdx.x;
    for (int i = tid; i < F1 * F2; i += 256) w2s[i] = W2[i];
    if (tid < F2) b2s[tid] = b2[tid];
    int nodeBase = blockIdx.x * 4;
    if (tid < 4 * F1) ts[tid] = t[(size_t)nodeBase * F1 + tid];
    __syncthreads();
    int w    = tid >> 6;
    int lane = tid & 63;
    int c = nodeBase + w;
    float sc = s[c];
    float v = -INFINITY;
    if (lane < F2) {
        float acc = sc * b2s[lane];
#pragma unroll
        for (int k = 0; k < F1; ++k)
            acc = fmaf(ts[w * F1 + k], w2s[k * F2 + lane], acc);
        v = acc;
    }
    float m = v;
#pragma unroll
    for (int off = 32; off; off >>= 1)
        m = fmaxf(m, __shfl_xor(m, off, 64));
    float ex = (lane < F2) ? expf(v - m) : 0.0f;
    float ssum = ex;
#pragma unroll
    for (int off = 32; off; off >>= 1)
        ssum += __shfl_xor(ssum, off, 64);
    if (lane < F2) out[(size_t)c * F2 + lane] = v - m - logf(ssum);
}

extern "C" void kernel_launch(void* const* d_in, const int* in_sizes, int n_in,
                              void* d_out, int out_size, void* d_ws, size_t ws_size,
                              hipStream_t stream) {
    const float* x   = (const float*)d_in[0];
    const int*   ei  = (const int*)d_in[1];
    const float* W1  = (const float*)d_in[2];
    const float* b1  = (const float*)d_in[3];
    const float* W2  = (const float*)d_in[4];
    const float* b2  = (const float*)d_in[5];
    float* out = (float*)d_out;

    const int* row = ei;             // edge_index[0]
    const int* col = ei + N_EDGES;   // edge_index[1]

    // workspace layout (4B words), P = 102400; total ~37.2 MB
    const size_t P = 102400;
    float* fws = (float*)d_ws;
    float* dis = fws;                                  // P
    float* s   = dis + P;                              // P
    int* start = (int*)(s + P);                        // P
    int* cnt   = start + P;                            // P
    int* gcur1 = cnt + P;                              // 256
    int* oscur = gcur1 + 256;                          // 8
    int2* stash = (int2*)(oscur + 8);                  // STASH int2 = 8192 words
    int* rows_sorted = (int*)(oscur + 8) + 2 * STASH;  // 196*CAPR = 3,462,144 words
    // deg8 (8P = 819200 words) aliases rows_sorted head: dis_kernel runs before csr2
    int* deg8 = rows_sorted;
    int* staging1 = rows_sorted + (size_t)NB1 * CAPR;  // 196*CAP1 = 4,221,056 words
    // staging1 dead after csr2: h1t (16P) + t (16P) alias it; g after
    float* h1t = (float*)staging1;
    float* t   = (float*)staging1 + 16 * P;
    float* g   = (float*)(staging1 + (size_t)NB1 * CAP1);  // 16P

    const int B = 256;

    // ---- graph build ----
    init_kernel<<<(8 * (int)P + B - 1) / B, B, 0, stream>>>(deg8, gcur1, oscur);
    bin_kernel<<<NWG1, B, 0, stream>>>(row, col, deg8, gcur1, oscur, stash, staging1);
    dis_kernel<<<(N_NODES + B - 1) / B, B, 0, stream>>>(deg8, dis);
    csr2_kernel<<<NB1, B, 0, stream>>>(staging1, gcur1, oscur, stash,
                                       start, cnt, rows_sorted);

    // ---- layer 1: h1t = dis*(x@W1+b1) ; g~ = dis*relu(dis*A-sum) --------
    mm1_kernel<<<(N_NODES + BR - 1) / BR, B, 0, stream>>>(x, W1, b1, dis, h1t);
    agg1_kernel<<<(N_NODES * 4 + B - 1) / B, B, 0, stream>>>(
        rows_sorted, start, cnt, dis, h1t, g, s);

    // ---- layer 2 (W2 commuted past aggregation): t = A_hat g~ -----------
    agg2_kernel<<<(N_NODES * 4 + B - 1) / B, B, 0, stream>>>(
        rows_sorted, start, cnt, dis, g, t);

    // ---- out = log_softmax(t@W2 + s*b2) ----
    mm2lsm_kernel<<<N_NODES / 4, B, 0, stream>>>(t, s, W2, b2, out);
}

// Round 4
// 822.222 us; speedup vs baseline: 1.0820x; 1.0820x over previous
//
#include <hip/hip_runtime.h>
#include <math.h>

#define N_NODES 100000
#define N_EDGES 3200000
#define F_IN    512
#define F1      16
#define F2      40

#define N_BUCKETS 6250    // node>>4 buckets; 6250*16 == 100000 exactly
#define NPART     8       // writer partitions == physical XCDs (HW_REG_XCC_ID)
#define CAPP      96      // per (part,bucket) staging cap; mean 64, sigma 8 -> 4 sigma, stash catches tail
#define CAPB      768     // rows_sorted fixed window/bucket; mean 512, sigma ~23 -> 11 sigma
#define STASH     4096    // global overflow stash (expected use: ~0-50 entries)

// mm1 tiling
#define BR 256
#define KK 32
#define XPITCH 36

__device__ __forceinline__ int xcc_id() {
    unsigned x;
    asm volatile("s_getreg_b32 %0, hwreg(HW_REG_XCC_ID)" : "=s"(x));
    return (int)(x & (NPART - 1));
}

// L2-local atomic: workgroup scope -> plain global_atomic_add, executes at the
// XCD's own L2 (no IC fabric round-trip, no 32B fabric write per op). Sound
// because each target cell is written ONLY by waves of that XCD (part=XCC_ID),
// and the local L2 is their common coherence point. R0-R3 counters showed
// device-scope atomics cost ~32B WRITE_SIZE + ~40ns each; this removes both.
__device__ __forceinline__ int atomicAddL2(int* p, int v) {
    return __hip_atomic_fetch_add(p, v, __ATOMIC_RELAXED, __HIP_MEMORY_SCOPE_WORKGROUP);
}

// ------- layer-1 matmul, LDS-tiled: h1t[r] = dis[r]*(x[r]@W1 + b1) -------
__global__ __launch_bounds__(256, 4) void mm1_kernel(
        const float* __restrict__ x, const float* __restrict__ W1,
        const float* __restrict__ b1, const float* __restrict__ dis,
        float* __restrict__ h1t) {
    __shared__ float xs[BR * XPITCH];
    __shared__ float ws[KK * F1];
    int t = threadIdx.x;
    int rbase = blockIdx.x * BR;
    int jq = t & 3;
    int rg = t >> 2;
    float acc[4][4];
#pragma unroll
    for (int i = 0; i < 4; ++i)
#pragma unroll
        for (int j = 0; j < 4; ++j) acc[i][j] = 0.0f;

    for (int ch = 0; ch < F_IN / KK; ++ch) {
        int c0 = ch * KK;
#pragma unroll
        for (int i = 0; i < 8; ++i) {
            int p  = t + i * 256;
            int tr = p >> 3;
            int f4 = p & 7;
            float4 v = make_float4(0.0f, 0.0f, 0.0f, 0.0f);
            int grow = rbase + tr;
            if (grow < N_NODES)
                v = *(const float4*)(x + (size_t)grow * F_IN + c0 + f4 * 4);
            *(float4*)&xs[tr * XPITCH + f4 * 4] = v;
        }
        if (t < 128) {
            int kk = t >> 2, f4 = t & 3;
            *(float4*)&ws[kk * F1 + f4 * 4] =
                *(const float4*)(W1 + (size_t)(c0 + kk) * F1 + f4 * 4);
        }
        __syncthreads();
#pragma unroll
        for (int k4 = 0; k4 < KK / 4; ++k4) {
            float xa[4][4], wa[4][4];
#pragma unroll
            for (int i = 0; i < 4; ++i)
                *(float4*)&xa[i][0] =
                    *(const float4*)&xs[(rg * 4 + i) * XPITCH + k4 * 4];
#pragma unroll
            for (int m = 0; m < 4; ++m)
                *(float4*)&wa[m][0] =
                    *(const float4*)&ws[(k4 * 4 + m) * F1 + jq * 4];
#pragma unroll
            for (int i = 0; i < 4; ++i)
#pragma unroll
                for (int m = 0; m < 4; ++m)
#pragma unroll
                    for (int j = 0; j < 4; ++j)
                        acc[i][j] = fmaf(xa[i][m], wa[m][j], acc[i][j]);
        }
        __syncthreads();
    }

    float4 bv = *(const float4*)(b1 + jq * 4);
#pragma unroll
    for (int i = 0; i < 4; ++i) {
        int grow = rbase + rg * 4 + i;
        if (grow < N_NODES) {
            float d = dis[grow];
            float4 o;
            o.x = d * (acc[i][0] + bv.x);
            o.y = d * (acc[i][1] + bv.y);
            o.z = d * (acc[i][2] + bv.z);
            o.w = d * (acc[i][3] + bv.w);
            *(float4*)(h1t + (size_t)grow * F1 + jq * 4) = o;
        }
    }
}

// ---------------- init: zero deg8 + cursors ------------------------------
__global__ void init_kernel(int* __restrict__ deg8, int* __restrict__ bcur,
                            int* __restrict__ scur) {
    int i = blockIdx.x * blockDim.x + threadIdx.x;
    if (i < NPART * 102400) deg8[i] = 0;
    if (i < NPART * N_BUCKETS) bcur[i] = 0;
    if (i == 0) *scur = 0;
}

// ---- bin: one thread per edge (12500 WGs, full occupancy). Payload
// r|low4(c) appended to staging[part][bucket][CAPP], cursor and degree
// counters bumped with L2-LOCAL (workgroup-scope) atomics. Rare cell
// overflow -> global stash via device atomic (~0-50 total).
__global__ __launch_bounds__(256) void bin_kernel(
        const int* __restrict__ row, const int* __restrict__ col,
        int* __restrict__ deg8, int* __restrict__ bcur, int* __restrict__ scur,
        int2* __restrict__ stash, int* __restrict__ staging) {
    int e = blockIdx.x * blockDim.x + threadIdx.x;
    if (e >= N_EDGES) return;
    int part = xcc_id();
    int r = row[e];
    int c = col[e];
    atomicAddL2(&deg8[part * 102400 + r], 1);
    int bc = c >> 4;
    int payload = r | ((c & 15) << 27);
    int cell = part * N_BUCKETS + bc;
    int pos = atomicAddL2(&bcur[cell], 1);
    if (pos < CAPP) {
        staging[(size_t)cell * CAPP + pos] = payload;
    } else {
        int sp = atomicAdd(scur, 1);               // device scope: rare path
        if (sp < STASH) stash[sp] = make_int2(bc, payload);
    }
}

// ---- dis = (deg+1)^-0.5 (+1 self loop); deg = sum of 8 per-XCD copies ---
__global__ void dis_kernel(const int* __restrict__ deg8, float* __restrict__ dis) {
    int i = blockIdx.x * blockDim.x + threadIdx.x;
    if (i < N_NODES) {
        int d = 1;
#pragma unroll
        for (int p = 0; p < NPART; ++p) d += deg8[p * 102400 + i];
        dis[i] = rsqrtf((float)d);
    }
}

// ---- csr: per-bucket finalize. Reads the bucket's 8 part cells + stash,
// 16-bin LDS histogram -> scan -> LDS scatter into ebuf, then streams
// rows_sorted out COALESCED into a fixed-stride window b*CAPB (no global
// scan needed). Replaces R2's 3.2M scattered 4B global writes.
__global__ __launch_bounds__(256) void csr_kernel(
        const int* __restrict__ staging, const int* __restrict__ bcur,
        const int* __restrict__ scur, const int2* __restrict__ stash,
        int* __restrict__ start, int* __restrict__ cnt,
        int* __restrict__ rows_sorted) {
    __shared__ int ebuf[CAPB];
    __shared__ int cnt16[16], off16[16], cur16[16];
    int b = blockIdx.x, t = threadIdx.x;
    if (t < 16) { cnt16[t] = 0; cur16[t] = 0; }
    __syncthreads();
    int szs[NPART];
#pragma unroll
    for (int p = 0; p < NPART; ++p) szs[p] = min(bcur[p * N_BUCKETS + b], CAPP);
    int ns = min(*scur, STASH);
#pragma unroll
    for (int p = 0; p < NPART; ++p) {
        const int* sb = staging + (size_t)(p * N_BUCKETS + b) * CAPP;
        for (int k = t; k < szs[p]; k += 256)
            atomicAdd(&cnt16[(sb[k] >> 27) & 15], 1);
    }
    for (int k = t; k < ns; k += 256) {
        int2 se = stash[k];
        if (se.x == b) atomicAdd(&cnt16[(se.y >> 27) & 15], 1);
    }
    __syncthreads();
    if (t == 0) {
        int s = 0;
#pragma unroll
        for (int i = 0; i < 16; ++i) { off16[i] = s; s += cnt16[i]; }
    }
    __syncthreads();
    if (t < 16) {
        start[b * 16 + t] = b * CAPB + off16[t];
        int room = CAPB - off16[t];
        cnt[b * 16 + t]   = min(cnt16[t], max(room, 0));   // defensive clamp
    }
    __syncthreads();
#pragma unroll
    for (int p = 0; p < NPART; ++p) {
        const int* sb = staging + (size_t)(p * N_BUCKETS + b) * CAPP;
        for (int k = t; k < szs[p]; k += 256) {
            int entry = sb[k];
            int c4 = (entry >> 27) & 15;
            int pos = atomicAdd(&cur16[c4], 1);
            int dst = off16[c4] + pos;
            if (dst < CAPB) ebuf[dst] = entry & 0x07FFFFFF;
        }
    }
    for (int k = t; k < ns; k += 256) {
        int2 se = stash[k];
        if (se.x == b) {
            int c4 = (se.y >> 27) & 15;
            int pos = atomicAdd(&cur16[c4], 1);
            int dst = off16[c4] + pos;
            if (dst < CAPB) ebuf[dst] = se.y & 0x07FFFFFF;
        }
    }
    __syncthreads();
    int total = min(off16[15] + cnt16[15], CAPB);
    int* outp = rows_sorted + (size_t)b * CAPB;
    for (int k = t; k < total; k += 256) outp[k] = ebuf[k];   // coalesced
}

// ------- layer-1 aggregation (dis-folded) + relu + row-sum s -------------
__global__ void agg1_kernel(const int* __restrict__ rows_sorted,
                            const int* __restrict__ start, const int* __restrict__ cnt,
                            const float* __restrict__ dis, const float* __restrict__ h1t,
                            float* __restrict__ g, float* __restrict__ s_out) {
    int idx = blockIdx.x * blockDim.x + threadIdx.x;
    if (idx >= N_NODES * 4) return;
    int c = idx >> 2;
    int q = idx & 3;
    float dc = dis[c];
    const float4* h4 = (const float4*)h1t;
    float4 acc = h4[(size_t)c * 4 + q];
    float ss = dc;
    int k0 = start[c];
    int k1 = k0 + cnt[c];
    for (int k = k0; k < k1; ++k) {
        int r = rows_sorted[k];
        float4 v = h4[(size_t)r * 4 + q];
        acc.x += v.x; acc.y += v.y; acc.z += v.z; acc.w += v.w;
        if (q == 0) ss += dis[r];
    }
    acc.x = dc * fmaxf(acc.x * dc, 0.0f);
    acc.y = dc * fmaxf(acc.y * dc, 0.0f);
    acc.z = dc * fmaxf(acc.z * dc, 0.0f);
    acc.w = dc * fmaxf(acc.w * dc, 0.0f);
    ((float4*)g)[(size_t)c * 4 + q] = acc;
    if (q == 0) s_out[c] = dc * ss;
}

// ---------------- layer-2 aggregation (dis-folded): t = A_hat g ----------
__global__ void agg2_kernel(const int* __restrict__ rows_sorted,
                            const int* __restrict__ start, const int* __restrict__ cnt,
                            const float* __restrict__ dis, const float* __restrict__ g,
                            float* __restrict__ t) {
    int idx = blockIdx.x * blockDim.x + threadIdx.x;
    if (idx >= N_NODES * 4) return;
    int c = idx >> 2;
    int q = idx & 3;
    float dc = dis[c];
    const float4* h4 = (const float4*)g;
    float4 acc = h4[(size_t)c * 4 + q];
    int k0 = start[c];
    int k1 = k0 + cnt[c];
    for (int k = k0; k < k1; ++k) {
        int r = rows_sorted[k];
        float4 v = h4[(size_t)r * 4 + q];
        acc.x += v.x; acc.y += v.y; acc.z += v.z; acc.w += v.w;
    }
    acc.x *= dc; acc.y *= dc; acc.z *= dc; acc.w *= dc;
    ((float4*)t)[(size_t)c * 4 + q] = acc;
}

// ------- fused: out = log_softmax(t @ W2 + s*b2^T), wave per node ---------
__global__ void mm2lsm_kernel(const float* __restrict__ t, const float* __restrict__ s,
                              const float* __restrict__ W2, const float* __restrict__ b2,
                              float* __restrict__ out) {
    __shared__ float w2s[F1 * F2];
    __shared__ float b2s[F2];
    __shared__ float ts[4 * F1];
    int tid = threadIdx.x;
    for (int i = tid; i < F1 * F2; i += 256) w2s[i] = W2[i];
    if (tid < F2) b2s[tid] = b2[tid];
    int nodeBase = blockIdx.x * 4;
    if (tid < 4 * F1) ts[tid] = t[(size_t)nodeBase * F1 + tid];
    __syncthreads();
    int w    = tid >> 6;
    int lane = tid & 63;
    int c = nodeBase + w;
    float sc = s[c];
    float v = -INFINITY;
    if (lane < F2) {
        float acc = sc * b2s[lane];
#pragma unroll
        for (int k = 0; k < F1; ++k)
            acc = fmaf(ts[w * F1 + k], w2s[k * F2 + lane], acc);
        v = acc;
    }
    float m = v;
#pragma unroll
    for (int off = 32; off; off >>= 1)
        m = fmaxf(m, __shfl_xor(m, off, 64));
    float ex = (lane < F2) ? expf(v - m) : 0.0f;
    float ssum = ex;
#pragma unroll
    for (int off = 32; off; off >>= 1)
        ssum += __shfl_xor(ssum, off, 64);
    if (lane < F2) out[(size_t)c * F2 + lane] = v - m - logf(ssum);
}

extern "C" void kernel_launch(void* const* d_in, const int* in_sizes, int n_in,
                              void* d_out, int out_size, void* d_ws, size_t ws_size,
                              hipStream_t stream) {
    const float* x   = (const float*)d_in[0];
    const int*   ei  = (const int*)d_in[1];
    const float* W1  = (const float*)d_in[2];
    const float* b1  = (const float*)d_in[3];
    const float* W2  = (const float*)d_in[4];
    const float* b2  = (const float*)d_in[5];
    float* out = (float*)d_out;

    const int* row = ei;             // edge_index[0]
    const int* col = ei + N_EDGES;   // edge_index[1]

    // workspace layout (4B words), P = 102400; total = 10,068,032 w = 40.27 MB
    const size_t P = 102400;
    float* fws = (float*)d_ws;
    float* dis = fws;                                  // P
    float* s   = dis + P;                              // P
    int* start = (int*)(s + P);                        // P
    int* cnt   = start + P;                            // P
    int* bcur  = cnt + P;                              // NPART*N_BUCKETS = 50000 (pad to 50176)
    int* scur  = bcur + 50176;                         // 64 (1 used)
    int2* stash = (int2*)(scur + 64);                  // STASH int2 = 8192 words
    int* rows_sorted = (int*)(scur + 64) + 2 * STASH;  // 6250*CAPB = 4,800,000 words
    // deg8 (8P = 819200 w) aliases rows_sorted head: dead before csr writes it
    int* deg8 = rows_sorted;
    int* staging = rows_sorted + (size_t)N_BUCKETS * CAPB;  // 8*6250*96 = 4,800,000 words
    // staging dead after csr: h1t (16P) + t (16P) + g (16P) = 4,915,200... fits via exact split:
    float* h1t = (float*)staging;                      // 16P = 1,638,400
    float* t   = (float*)staging + 16 * P;             // 16P
    float* g   = (float*)staging + 32 * P;             // needs 16P; staging is 4.8Mw = 46.875P -> g gets 14.875P?
    // NOTE: 3*16P = 4,915,200 > 4,800,000. Shift g into the stash+cursor slack is unsafe;
    // instead place g in the bcur..stash region? Too small. Solution: t and g swap so the
    // overflow lands on t? No — keep it simple: lower CAPB usage for alias only:
    // h1t and t in staging (32P = 3,276,800 <= 4,800,000 OK), g overlaps rows_sorted? NO.
    // g placed at staging + 32P, using remaining 1,523,200 w + 115,200 w spill past staging
    // end would exceed workspace. Use the unused tail: total ws = 40.27MB; we still have
    // the gap between required 10,068,032 w and... none. Final: shrink g's source:
    // g = dis-folded relu output, 16P needed. Re-point g to alias deg8/rows_sorted? rows_sorted
    // is live during agg. Correct fix: g shares the FIRST 16P of staging with h1t? h1t is
    // still read by agg1 while g is written. Disjoint requirement: h1t(read), g(write) in agg1;
    // g(read), t(write) in agg2; t(read) in mm2. So {h1t,g} disjoint, {g,t} disjoint, but
    // h1t and t CAN share memory (h1t dead after agg1, t written in agg2):
    //   h1t = staging + 0       (16P)
    //   g   = staging + 16P     (16P)
    //   t   = staging + 0       (alias h1t; h1t dead when agg2 writes t)
    t = (float*)staging;                               // alias h1t (dead after agg1)
    g = (float*)staging + 16 * P;                      // 16P; 32P total <= 4.8M w  ✓

    const int B = 256;
    const int gridE = (N_EDGES + B - 1) / B;

    // ---- graph build ----
    init_kernel<<<(NPART * (int)P + B - 1) / B, B, 0, stream>>>(deg8, bcur, scur);
    bin_kernel<<<gridE, B, 0, stream>>>(row, col, deg8, bcur, scur, stash, staging);
    dis_kernel<<<(N_NODES + B - 1) / B, B, 0, stream>>>(deg8, dis);
    csr_kernel<<<N_BUCKETS, B, 0, stream>>>(staging, bcur, scur, stash,
                                            start, cnt, rows_sorted);

    // ---- layer 1: h1t = dis*(x@W1+b1) ; g~ = dis*relu(dis*A-sum) --------
    mm1_kernel<<<(N_NODES + BR - 1) / BR, B, 0, stream>>>(x, W1, b1, dis, h1t);
    agg1_kernel<<<(N_NODES * 4 + B - 1) / B, B, 0, stream>>>(
        rows_sorted, start, cnt, dis, h1t, g, s);

    // ---- layer 2 (W2 commuted past aggregation): t = A_hat g~ -----------
    agg2_kernel<<<(N_NODES * 4 + B - 1) / B, B, 0, stream>>>(
        rows_sorted, start, cnt, dis, g, t);

    // ---- out = log_softmax(t@W2 + s*b2) ----
    mm2lsm_kernel<<<N_NODES / 4, B, 0, stream>>>(t, s, W2, b2, out);
}

// Round 6
// 791.377 us; speedup vs baseline: 1.1242x; 1.0390x over previous
//
#include <hip/hip_runtime.h>
#include <math.h>

#define N_NODES 100000
#define N_EDGES 3200000
#define F_IN    512
#define F1      16
#define F2      40

// graph build: 196 coarse buckets of 512 nodes (key >> 9)
#define NB      196
#define NWGA    400       // bin workgroups; CHUNK*NWGA == N_EDGES exactly
#define CHUNK   8000
#define BATCH   512       // edges per WG batch (2 per thread)
#define NBATCH  16        // ceil(CHUNK/BATCH)
#define BDEPTH  32        // LDS buffer depth per col-bucket (ints, 2 lines)
#define BDEPTHB 64        // LDS buffer depth per row-bucket (ushorts, 2 lines)
#define CAP1    23408     // col staging/bucket: 16327 mean + 400*15 pads + 8sig, 16-aligned
#define CAPB1   29824     // row staging/bucket (ushorts): mean + 400*31 pads + 8sig, 32-aligned
#define CAPR    17664     // rows_sorted window/bucket: mean + 10 sigma
#define STASH   4096      // overflow stash (expected use ~0)

// mm1 tiling
#define BR 256
#define KK 32
#define XPITCH 36

// ------- layer-1 matmul, LDS-tiled: h1t[r] = dis[r]*(x[r]@W1 + b1) -------
__global__ __launch_bounds__(256, 4) void mm1_kernel(
        const float* __restrict__ x, const float* __restrict__ W1,
        const float* __restrict__ b1, const float* __restrict__ dis,
        float* __restrict__ h1t) {
    __shared__ float xs[BR * XPITCH];
    __shared__ float ws[KK * F1];
    int t = threadIdx.x;
    int rbase = blockIdx.x * BR;
    int jq = t & 3;
    int rg = t >> 2;
    float acc[4][4];
#pragma unroll
    for (int i = 0; i < 4; ++i)
#pragma unroll
        for (int j = 0; j < 4; ++j) acc[i][j] = 0.0f;

    for (int ch = 0; ch < F_IN / KK; ++ch) {
        int c0 = ch * KK;
#pragma unroll
        for (int i = 0; i < 8; ++i) {
            int p  = t + i * 256;
            int tr = p >> 3;
            int f4 = p & 7;
            float4 v = make_float4(0.0f, 0.0f, 0.0f, 0.0f);
            int grow = rbase + tr;
            if (grow < N_NODES)
                v = *(const float4*)(x + (size_t)grow * F_IN + c0 + f4 * 4);
            *(float4*)&xs[tr * XPITCH + f4 * 4] = v;
        }
        if (t < 128) {
            int kk = t >> 2, f4 = t & 3;
            *(float4*)&ws[kk * F1 + f4 * 4] =
                *(const float4*)(W1 + (size_t)(c0 + kk) * F1 + f4 * 4);
        }
        __syncthreads();
#pragma unroll
        for (int k4 = 0; k4 < KK / 4; ++k4) {
            float xa[4][4], wa[4][4];
#pragma unroll
            for (int i = 0; i < 4; ++i)
                *(float4*)&xa[i][0] =
                    *(const float4*)&xs[(rg * 4 + i) * XPITCH + k4 * 4];
#pragma unroll
            for (int m = 0; m < 4; ++m)
                *(float4*)&wa[m][0] =
                    *(const float4*)&ws[(k4 * 4 + m) * F1 + jq * 4];
#pragma unroll
            for (int i = 0; i < 4; ++i)
#pragma unroll
                for (int m = 0; m < 4; ++m)
#pragma unroll
                    for (int j = 0; j < 4; ++j)
                        acc[i][j] = fmaf(xa[i][m], wa[m][j], acc[i][j]);
        }
        __syncthreads();
    }

    float4 bv = *(const float4*)(b1 + jq * 4);
#pragma unroll
    for (int i = 0; i < 4; ++i) {
        int grow = rbase + rg * 4 + i;
        if (grow < N_NODES) {
            float d = dis[grow];
            float4 o;
            o.x = d * (acc[i][0] + bv.x);
            o.y = d * (acc[i][1] + bv.y);
            o.z = d * (acc[i][2] + bv.z);
            o.w = d * (acc[i][3] + bv.w);
            *(float4*)(h1t + (size_t)grow * F1 + jq * 4) = o;
        }
    }
}

// ---------------- init: zero cursors (tiny) ------------------------------
__global__ void init_kernel(int* __restrict__ gcurA, int* __restrict__ gcurB,
                            int* __restrict__ scurA, int* __restrict__ scurB) {
    int i = threadIdx.x;
    gcurA[i] = 0;
    gcurB[i] = 0;
    if (i == 0) { *scurA = 0; *scurB = 0; }
}

// ---- binA: col-side LDS line-buffered radix to 196 coarse buckets.
// ZERO per-edge global atomics (R0-R4 counters: each global atomic = one
// ~32B memory-side write, chip ceiling ~25G atomics/s = the entire bin
// cost). Global atomics only for per-flush window reservation (~300K
// total). Every staging line is written completely by one wave -> clean
// full-line evictions, payload-only WRITE_SIZE.
__global__ __launch_bounds__(256) void binA_kernel(
        const int* __restrict__ row, const int* __restrict__ col,
        int* __restrict__ gcurA, int* __restrict__ scurA,
        int2* __restrict__ stashA, int* __restrict__ stagingA) {
    __shared__ __align__(16) int buf[NB][BDEPTH];     // 25 KB
    __shared__ int cur[NB];
    __shared__ int myBase[NB];
    __shared__ short flushList[2 * NB];
    __shared__ int flushCnt;
    int t = threadIdx.x;
    for (int i = t; i < NB; i += 256) cur[i] = 0;
    if (t == 0) flushCnt = 0;
    __syncthreads();
    int e0 = blockIdx.x * CHUNK;
    for (int batch = 0; batch <= NBATCH; ++batch) {
        if (batch < NBATCH) {
#pragma unroll
            for (int u = 0; u < 2; ++u) {
                int e = e0 + batch * BATCH + u * 256 + t;
                if (e < e0 + CHUNK) {
                    int r = row[e];
                    int c = col[e];
                    int bb = c >> 9;
                    int payload = r | ((c & 511) << 17);   // r fits 17 bits
                    int pos = atomicAdd(&cur[bb], 1);      // LDS atomic (free)
                    if (pos < BDEPTH) buf[bb][pos] = payload;
                    else { int sp = atomicAdd(scurA, 1);   // rare
                           if (sp < STASH) stashA[sp] = make_int2(bb, payload); }
                }
            }
        } else {
            // drain: pad remainder to a full 16-entry line with -1 sentinels
            if (t < NB) {
                int rem = min(cur[t], BDEPTH);
                if (rem & 15) {
                    int up = (rem + 15) & ~15;
                    for (int i = rem; i < up; ++i) buf[t][i] = -1;
                    cur[t] = up;
                } else cur[t] = rem;
            }
        }
        __syncthreads();
        if (t < NB) {
            int n = min(cur[t], BDEPTH);
            int lines = n >> 4;
            if (lines) {
                int base = atomicAdd(&gcurA[t], lines * 16);
                if (base + lines * 16 <= CAP1) {
                    myBase[t] = base;
                    int li = atomicAdd(&flushCnt, lines);
                    for (int L = 0; L < lines; ++L)
                        flushList[li + L] = (short)((t << 2) | L);
                } else {                                   // statistically never
                    for (int i = 0; i < lines * 16; ++i) {
                        int v = buf[t][i];
                        if (v != -1) {
                            int sp = atomicAdd(scurA, 1);
                            if (sp < STASH) stashA[sp] = make_int2(t, v);
                        }
                    }
                }
            }
        }
        __syncthreads();
        int fc = flushCnt;
        for (int j = t; j < fc * 4; j += 256) {
            int gd = flushList[j >> 2];
            int lane4 = j & 3;
            int bb = gd >> 2, L = gd & 3;
            int4 v = *(int4*)&buf[bb][L * 16 + lane4 * 4];
            *(int4*)&stagingA[(size_t)bb * CAP1 + myBase[bb] + L * 16 + lane4 * 4] = v;
        }
        __syncthreads();
        if (t < NB) {
            int n = min(cur[t], BDEPTH);
            int lines = n >> 4, rem = n & 15;
            if (lines) for (int i = 0; i < rem; ++i) buf[t][i] = buf[t][lines * 16 + i];
            cur[t] = rem;
        }
        if (t == 0) flushCnt = 0;
        __syncthreads();
    }
}

// ---- binB: row-side radix (2-byte payload r&511) for degree counting.
// Same zero-per-edge-atomic machinery; replaces the 3.2M deg atomics.
__global__ __launch_bounds__(256) void binB_kernel(
        const int* __restrict__ row,
        int* __restrict__ gcurB, int* __restrict__ scurB,
        int2* __restrict__ stashB, unsigned short* __restrict__ stagingB) {
    __shared__ __align__(16) unsigned short buf[NB][BDEPTHB];   // 25 KB
    __shared__ int cur[NB];
    __shared__ int myBase[NB];
    __shared__ short flushList[2 * NB];
    __shared__ int flushCnt;
    int t = threadIdx.x;
    for (int i = t; i < NB; i += 256) cur[i] = 0;
    if (t == 0) flushCnt = 0;
    __syncthreads();
    int e0 = blockIdx.x * CHUNK;
    for (int batch = 0; batch <= NBATCH; ++batch) {
        if (batch < NBATCH) {
#pragma unroll
            for (int u = 0; u < 2; ++u) {
                int e = e0 + batch * BATCH + u * 256 + t;
                if (e < e0 + CHUNK) {
                    int r = row[e];
                    int bb = r >> 9;
                    unsigned short payload = (unsigned short)(r & 511);
                    int pos = atomicAdd(&cur[bb], 1);
                    if (pos < BDEPTHB) buf[bb][pos] = payload;
                    else { int sp = atomicAdd(scurB, 1);
                           if (sp < STASH) stashB[sp] = make_int2(bb, (int)payload); }
                }
            }
        } else {
            if (t < NB) {
                int rem = min(cur[t], BDEPTHB);
                if (rem & 31) {
                    int up = (rem + 31) & ~31;
                    for (int i = rem; i < up; ++i) buf[t][i] = 0xFFFF;
                    cur[t] = up;
                } else cur[t] = rem;
            }
        }
        __syncthreads();
        if (t < NB) {
            int n = min(cur[t], BDEPTHB);
            int lines = n >> 5;
            if (lines) {
                int base = atomicAdd(&gcurB[t], lines * 32);
                if (base + lines * 32 <= CAPB1) {
                    myBase[t] = base;
                    int li = atomicAdd(&flushCnt, lines);
                    for (int L = 0; L < lines; ++L)
                        flushList[li + L] = (short)((t << 2) | L);
                } else {
                    for (int i = 0; i < lines * 32; ++i) {
                        unsigned short v = buf[t][i];
                        if (v != 0xFFFF) {
                            int sp = atomicAdd(scurB, 1);
                            if (sp < STASH) stashB[sp] = make_int2(t, (int)v);
                        }
                    }
                }
            }
        }
        __syncthreads();
        int fc = flushCnt;
        for (int j = t; j < fc * 4; j += 256) {
            int gd = flushList[j >> 2];
            int lane4 = j & 3;
            int bb = gd >> 2, L = gd & 3;
            int4 v = *(int4*)&buf[bb][L * 32 + lane4 * 8];
            *(int4*)&stagingB[(size_t)bb * CAPB1 + myBase[bb] + L * 32 + lane4 * 8] = v;
        }
        __syncthreads();
        if (t < NB) {
            int n = min(cur[t], BDEPTHB);
            int lines = n >> 5, rem = n & 31;
            if (lines) for (int i = 0; i < rem; ++i) buf[t][i] = buf[t][lines * 32 + i];
            cur[t] = rem;
        }
        if (t == 0) flushCnt = 0;
        __syncthreads();
    }
}

// ---- degC: per row-bucket 512-counter LDS histogram -> dis directly -----
__global__ __launch_bounds__(256) void degC_kernel(
        const unsigned short* __restrict__ stagingB, const int* __restrict__ gcurB,
        const int* __restrict__ scurB, const int2* __restrict__ stashB,
        float* __restrict__ dis) {
    __shared__ int cnt512[512];
    int b = blockIdx.x, t = threadIdx.x;
    for (int i = t; i < 512; i += 256) cnt512[i] = 0;
    __syncthreads();
    const unsigned short* sb = stagingB + (size_t)b * CAPB1;
    int n = min(gcurB[b], CAPB1);
    for (int k = t; k < n; k += 256) {
        unsigned short p = sb[k];
        if (p != 0xFFFF) atomicAdd(&cnt512[p], 1);
    }
    int ns = min(*scurB, STASH);
    for (int k = t; k < ns; k += 256) {
        int2 se = stashB[k];
        if (se.x == b) atomicAdd(&cnt512[se.y], 1);
    }
    __syncthreads();
    for (int i = t; i < 512; i += 256) {
        int node = b * 512 + i;
        if (node < N_NODES) dis[node] = rsqrtf((float)(cnt512[i] + 1));  // +1 self loop
    }
}

// ---- csr2: per col-bucket, sort ~16-20K entries fully in LDS (512-counter
// histogram -> scan -> LDS scatter), stream rows_sorted out COALESCED into
// a fixed-stride window b*CAPR (no global scan, no scattered global writes).
__global__ __launch_bounds__(256) void csr2_kernel(
        const int* __restrict__ stagingA, const int* __restrict__ gcurA,
        const int* __restrict__ scurA, const int2* __restrict__ stashA,
        int* __restrict__ start, int* __restrict__ cnt,
        int* __restrict__ rows_sorted) {
    __shared__ int ebuf[CAPR];
    __shared__ int cnt512[512], off512[512], cur512[512];
    __shared__ int psum[256];
    int b = blockIdx.x, t = threadIdx.x;
    for (int i = t; i < 512; i += 256) { cnt512[i] = 0; cur512[i] = 0; }
    __syncthreads();
    const int* sb = stagingA + (size_t)b * CAP1;
    int n1 = min(gcurA[b], CAP1);
    for (int k = t; k < n1; k += 256) {
        int e = sb[k];
        if (e != -1) atomicAdd(&cnt512[(e >> 17) & 511], 1);
    }
    int ns = min(*scurA, STASH);
    for (int k = t; k < ns; k += 256) {
        int2 se = stashA[k];
        if (se.x == b && se.y != -1) atomicAdd(&cnt512[(se.y >> 17) & 511], 1);
    }
    __syncthreads();
    int a0 = cnt512[2 * t], a1 = cnt512[2 * t + 1];
    int ps = a0 + a1;
    psum[t] = ps;
    __syncthreads();
    for (int off = 1; off < 256; off <<= 1) {
        int v = (t >= off) ? psum[t - off] : 0;
        __syncthreads();
        psum[t] += v;
        __syncthreads();
    }
    int excl = psum[t] - ps;
    off512[2 * t] = excl;
    off512[2 * t + 1] = excl + a0;
    __syncthreads();
    for (int i = t; i < 512; i += 256) {
        int node = b * 512 + i;                    // max 100351 < 102400 (array pad)
        start[node] = b * CAPR + off512[i];
        int room = CAPR - off512[i];
        cnt[node]   = min(cnt512[i], max(room, 0));   // defensive clamp
    }
    for (int k = t; k < n1; k += 256) {
        int e = sb[k];
        if (e != -1) {
            int i = (e >> 17) & 511;
            int pos = atomicAdd(&cur512[i], 1);
            int dst = off512[i] + pos;
            if (dst < CAPR) ebuf[dst] = e & 0x1FFFF;
        }
    }
    for (int k = t; k < ns; k += 256) {
        int2 se = stashA[k];
        if (se.x == b && se.y != -1) {
            int i = (se.y >> 17) & 511;
            int pos = atomicAdd(&cur512[i], 1);
            int dst = off512[i] + pos;
            if (dst < CAPR) ebuf[dst] = se.y & 0x1FFFF;
        }
    }
    __syncthreads();
    int total = min(off512[511] + cnt512[511], CAPR);
    int* outp = rows_sorted + (size_t)b * CAPR;
    for (int k = t; k < total; k += 256) outp[k] = ebuf[k];   // coalesced
}

// ------- layer-1 aggregation (dis-folded) + relu + row-sum s -------------
__global__ void agg1_kernel(const int* __restrict__ rows_sorted,
                            const int* __restrict__ start, const int* __restrict__ cnt,
                            const float* __restrict__ dis, const float* __restrict__ h1t,
                            float* __restrict__ g, float* __restrict__ s_out) {
    int idx = blockIdx.x * blockDim.x + threadIdx.x;
    if (idx >= N_NODES * 4) return;
    int c = idx >> 2;
    int q = idx & 3;
    float dc = dis[c];
    const float4* h4 = (const float4*)h1t;
    float4 acc = h4[(size_t)c * 4 + q];
    float ss = dc;
    int k0 = start[c];
    int k1 = k0 + cnt[c];
    for (int k = k0; k < k1; ++k) {
        int r = rows_sorted[k];
        float4 v = h4[(size_t)r * 4 + q];
        acc.x += v.x; acc.y += v.y; acc.z += v.z; acc.w += v.w;
        if (q == 0) ss += dis[r];
    }
    acc.x = dc * fmaxf(acc.x * dc, 0.0f);
    acc.y = dc * fmaxf(acc.y * dc, 0.0f);
    acc.z = dc * fmaxf(acc.z * dc, 0.0f);
    acc.w = dc * fmaxf(acc.w * dc, 0.0f);
    ((float4*)g)[(size_t)c * 4 + q] = acc;
    if (q == 0) s_out[c] = dc * ss;
}

// ---------------- layer-2 aggregation (dis-folded): t = A_hat g ----------
__global__ void agg2_kernel(const int* __restrict__ rows_sorted,
                            const int* __restrict__ start, const int* __restrict__ cnt,
                            const float* __restrict__ dis, const float* __restrict__ g,
                            float* __restrict__ t) {
    int idx = blockIdx.x * blockDim.x + threadIdx.x;
    if (idx >= N_NODES * 4) return;
    int c = idx >> 2;
    int q = idx & 3;
    float dc = dis[c];
    const float4* h4 = (const float4*)g;
    float4 acc = h4[(size_t)c * 4 + q];
    int k0 = start[c];
    int k1 = k0 + cnt[c];
    for (int k = k0; k < k1; ++k) {
        int r = rows_sorted[k];
        float4 v = h4[(size_t)r * 4 + q];
        acc.x += v.x; acc.y += v.y; acc.z += v.z; acc.w += v.w;
    }
    acc.x *= dc; acc.y *= dc; acc.z *= dc; acc.w *= dc;
    ((float4*)t)[(size_t)c * 4 + q] = acc;
}

// ------- fused: out = log_softmax(t @ W2 + s*b2^T), wave per node ---------
__global__ void mm2lsm_kernel(const float* __restrict__ t, const float* __restrict__ s,
                              const float* __restrict__ W2, const float* __restrict__ b2,
                              float* __restrict__ out) {
    __shared__ float w2s[F1 * F2];
    __shared__ float b2s[F2];
    __shared__ float ts[4 * F1];
    int tid = threadIdx.x;
    for (int i = tid; i < F1 * F2; i += 256) w2s[i] = W2[i];
    if (tid < F2) b2s[tid] = b2[tid];
    int nodeBase = blockIdx.x * 4;
    if (tid < 4 * F1) ts[tid] = t[(size_t)nodeBase * F1 + tid];
    __syncthreads();
    int w    = tid >> 6;
    int lane = tid & 63;
    int c = nodeBase + w;
    float sc = s[c];
    float v = -INFINITY;
    if (lane < F2) {
        float acc = sc * b2s[lane];
#pragma unroll
        for (int k = 0; k < F1; ++k)
            acc = fmaf(ts[w * F1 + k], w2s[k * F2 + lane], acc);
        v = acc;
    }
    float m = v;
#pragma unroll
    for (int off = 32; off; off >>= 1)
        m = fmaxf(m, __shfl_xor(m, off, 64));
    float ex = (lane < F2) ? expf(v - m) : 0.0f;
    float ssum = ex;
#pragma unroll
    for (int off = 32; off; off >>= 1)
        ssum += __shfl_xor(ssum, off, 64);
    if (lane < F2) out[(size_t)c * F2 + lane] = v - m - logf(ssum);
}

extern "C" void kernel_launch(void* const* d_in, const int* in_sizes, int n_in,
                              void* d_out, int out_size, void* d_ws, size_t ws_size,
                              hipStream_t stream) {
    const float* x   = (const float*)d_in[0];
    const int*   ei  = (const int*)d_in[1];
    const float* W1  = (const float*)d_in[2];
    const float* b1  = (const float*)d_in[3];
    const float* W2  = (const float*)d_in[4];
    const float* b2  = (const float*)d_in[5];
    float* out = (float*)d_out;

    const int* row = ei;             // edge_index[0]
    const int* col = ei + N_EDGES;   // edge_index[1]

    // workspace layout (4B words), P = 102400; total ~8.48M words = 33.9 MB
    const size_t P = 102400;
    float* fws = (float*)d_ws;
    float* dis = fws;                                  // P
    float* s   = dis + P;                              // P
    int* start = (int*)(s + P);                        // P
    int* cnt   = start + P;                            // P
    int* gcurA = cnt + P;                              // 256
    int* gcurB = gcurA + 256;                          // 256
    int* scurA = gcurB + 256;                          // 64 (1 used)
    int* scurB = scurA + 64;                           // 64
    int2* stashA = (int2*)(scurB + 64);                // 2*STASH words
    int2* stashB = stashA + STASH;                     // 2*STASH words
    int* rows_sorted = (int*)(stashB + STASH);         // 196*CAPR = 3,462,144 words
    // stagingB (196*CAPB1 ushorts = 2,922,752 words) aliases rows_sorted:
    // degC (reads stagingB) runs BEFORE csr2 (writes rows_sorted).
    unsigned short* stagingB = (unsigned short*)rows_sorted;
    int* stagingA = rows_sorted + (size_t)NB * CAPR;   // 196*CAP1 = 4,587,968 words
    // stagingA dead after csr2; h1t (16P) + g (16P) alias it (32P <= 4.59M OK).
    // t aliases h1t (h1t dead after agg1, t written in agg2).
    float* h1t = (float*)stagingA;
    float* g   = (float*)stagingA + 16 * P;
    float* t   = (float*)stagingA;

    const int B = 256;

    // ---- graph build: zero-per-edge-atomic radix + local histograms ----
    init_kernel<<<1, B, 0, stream>>>(gcurA, gcurB, scurA, scurB);
    binA_kernel<<<NWGA, B, 0, stream>>>(row, col, gcurA, scurA, stashA, stagingA);
    binB_kernel<<<NWGA, B, 0, stream>>>(row, gcurB, scurB, stashB, stagingB);
    degC_kernel<<<NB, B, 0, stream>>>(stagingB, gcurB, scurB, stashB, dis);
    csr2_kernel<<<NB, B, 0, stream>>>(stagingA, gcurA, scurA, stashA,
                                      start, cnt, rows_sorted);

    // ---- layer 1: h1t = dis*(x@W1+b1) ; g~ = dis*relu(dis*A-sum) --------
    mm1_kernel<<<(N_NODES + BR - 1) / BR, B, 0, stream>>>(x, W1, b1, dis, h1t);
    agg1_kernel<<<(N_NODES * 4 + B - 1) / B, B, 0, stream>>>(
        rows_sorted, start, cnt, dis, h1t, g, s);

    // ---- layer 2 (W2 commuted past aggregation): t = A_hat g~ -----------
    agg2_kernel<<<(N_NODES * 4 + B - 1) / B, B, 0, stream>>>(
        rows_sorted, start, cnt, dis, g, t);

    // ---- out = log_softmax(t@W2 + s*b2) ----
    mm2lsm_kernel<<<N_NODES / 4, B, 0, stream>>>(t, s, W2, b2, out);
}

// Round 8
// 711.616 us; speedup vs baseline: 1.2502x; 1.1121x over previous
//
#include <hip/hip_runtime.h>
#include <math.h>

#define N_NODES 100000
#define N_EDGES 3200000
#define F_IN    512
#define F1      16
#define F2      40

// graph build: 196 coarse buckets of 512 nodes (key >> 9)
#define NB      196
#define NWGA    400       // bin workgroups; CHUNK*NWGA == N_EDGES exactly
#define CHUNK   8000
#define BATCH   512       // edges per WG batch (2 per thread)
#define NBATCH  16        // ceil(CHUNK/BATCH)
#define BDEPTH  32        // LDS buffer depth per col-bucket (ints, 2 lines)
#define BDEPTHB 64        // LDS buffer depth per row-bucket (ushorts, 2 lines)
#define CAP1    23408     // col staging/bucket: 16327 mean + 400*15 pads + 8sig, 16-aligned
#define CAPB1   29824     // row staging/bucket (ushorts): mean + 400*31 pads + 8sig, 32-aligned
#define CAPR    17664     // rows_sorted window/bucket: mean + 10 sigma
#define STASH   4096      // overflow stash (expected use ~0)

// mm1 tiling: BR=64 -> grid 1563 blocks (~6/CU). R6 counters: BR=256 gave
// 391 blocks = 1.5/CU = 16% occupancy, latency-bound at 172us (VALU 8%,
// HBM 9%). Smaller tile trades nothing (same coalescing) for 4x grid.
#define BR 64
#define KK 32
#define XPITCH 36

// ------- layer-1 matmul, LDS-tiled: h1t[r] = dis[r]*(x[r]@W1 + b1) -------
// thread = (row rg, col-quad jq); 1 row x 4 cols per thread.
// launch_bounds (256,4): no VGPR squeeze (128 cap); occupancy comes from
// the 4x bigger grid, not from forcing 8 waves/EU.
__global__ __launch_bounds__(256, 4) void mm1_kernel(
        const float* __restrict__ x, const float* __restrict__ W1,
        const float* __restrict__ b1, const float* __restrict__ dis,
        float* __restrict__ h1t) {
    __shared__ float xs[BR * XPITCH];   // 9 KB
    __shared__ float ws[KK * F1];       // 2 KB
    int t = threadIdx.x;
    int rbase = blockIdx.x * BR;
    int jq = t & 3;            // col-quad: cols jq*4..jq*4+3
    int rg = t >> 2;           // row 0..63
    float acc[4] = {0.0f, 0.0f, 0.0f, 0.0f};

    for (int ch = 0; ch < F_IN / KK; ++ch) {
        int c0 = ch * KK;
#pragma unroll
        for (int i = 0; i < 2; ++i) {      // 64 rows x 8 float4 / 256 thr = 2
            int p  = t + i * 256;
            int tr = p >> 3;
            int f4 = p & 7;
            float4 v = make_float4(0.0f, 0.0f, 0.0f, 0.0f);
            int grow = rbase + tr;
            if (grow < N_NODES)
                v = *(const float4*)(x + (size_t)grow * F_IN + c0 + f4 * 4);
            *(float4*)&xs[tr * XPITCH + f4 * 4] = v;
        }
        if (t < 128) {
            int kk = t >> 2, f4 = t & 3;
            *(float4*)&ws[kk * F1 + f4 * 4] =
                *(const float4*)(W1 + (size_t)(c0 + kk) * F1 + f4 * 4);
        }
        __syncthreads();
#pragma unroll
        for (int k4 = 0; k4 < KK / 4; ++k4) {
            float xa[4], wa[4][4];
            *(float4*)&xa[0] = *(const float4*)&xs[rg * XPITCH + k4 * 4];
#pragma unroll
            for (int m = 0; m < 4; ++m)
                *(float4*)&wa[m][0] =
                    *(const float4*)&ws[(k4 * 4 + m) * F1 + jq * 4];
#pragma unroll
            for (int m = 0; m < 4; ++m)
#pragma unroll
                for (int j = 0; j < 4; ++j)
                    acc[j] = fmaf(xa[m], wa[m][j], acc[j]);
        }
        __syncthreads();
    }

    int grow = rbase + rg;
    if (grow < N_NODES) {
        float4 bv = *(const float4*)(b1 + jq * 4);
        float d = dis[grow];
        float4 o;
        o.x = d * (acc[0] + bv.x);
        o.y = d * (acc[1] + bv.y);
        o.z = d * (acc[2] + bv.z);
        o.w = d * (acc[3] + bv.w);
        *(float4*)(h1t + (size_t)grow * F1 + jq * 4) = o;
    }
}

// ---------------- init: zero cursors (tiny) ------------------------------
__global__ void init_kernel(int* __restrict__ gcurA, int* __restrict__ gcurB,
                            int* __restrict__ scurA, int* __restrict__ scurB) {
    int i = threadIdx.x;
    gcurA[i] = 0;
    gcurB[i] = 0;
    if (i == 0) { *scurA = 0; *scurB = 0; }
}

// ---- binA: col-side LDS line-buffered radix to 196 coarse buckets.
// ZERO per-edge global atomics (R0-R4 counters: each global atomic = one
// ~32B memory-side write, chip ceiling ~25G atomics/s = the entire bin
// cost). Global atomics only for per-flush window reservation (~300K
// total). Every staging line is written completely by one wave -> clean
// full-line evictions, payload-only WRITE_SIZE.
__global__ __launch_bounds__(256) void binA_kernel(
        const int* __restrict__ row, const int* __restrict__ col,
        int* __restrict__ gcurA, int* __restrict__ scurA,
        int2* __restrict__ stashA, int* __restrict__ stagingA) {
    __shared__ __align__(16) int buf[NB][BDEPTH];     // 25 KB
    __shared__ int cur[NB];
    __shared__ int myBase[NB];
    __shared__ short flushList[2 * NB];
    __shared__ int flushCnt;
    int t = threadIdx.x;
    for (int i = t; i < NB; i += 256) cur[i] = 0;
    if (t == 0) flushCnt = 0;
    __syncthreads();
    int e0 = blockIdx.x * CHUNK;
    for (int batch = 0; batch <= NBATCH; ++batch) {
        if (batch < NBATCH) {
#pragma unroll
            for (int u = 0; u < 2; ++u) {
                int e = e0 + batch * BATCH + u * 256 + t;
                if (e < e0 + CHUNK) {
                    int r = row[e];
                    int c = col[e];
                    int bb = c >> 9;
                    int payload = r | ((c & 511) << 17);   // r fits 17 bits
                    int pos = atomicAdd(&cur[bb], 1);      // LDS atomic (free)
                    if (pos < BDEPTH) buf[bb][pos] = payload;
                    else { int sp = atomicAdd(scurA, 1);   // rare
                           if (sp < STASH) stashA[sp] = make_int2(bb, payload); }
                }
            }
        } else {
            // drain: pad remainder to a full 16-entry line with -1 sentinels
            if (t < NB) {
                int rem = min(cur[t], BDEPTH);
                if (rem & 15) {
                    int up = (rem + 15) & ~15;
                    for (int i = rem; i < up; ++i) buf[t][i] = -1;
                    cur[t] = up;
                } else cur[t] = rem;
            }
        }
        __syncthreads();
        if (t < NB) {
            int n = min(cur[t], BDEPTH);
            int lines = n >> 4;
            if (lines) {
                int base = atomicAdd(&gcurA[t], lines * 16);
                if (base + lines * 16 <= CAP1) {
                    myBase[t] = base;
                    int li = atomicAdd(&flushCnt, lines);
                    for (int L = 0; L < lines; ++L)
                        flushList[li + L] = (short)((t << 2) | L);
                } else {                                   // statistically never
                    for (int i = 0; i < lines * 16; ++i) {
                        int v = buf[t][i];
                        if (v != -1) {
                            int sp = atomicAdd(scurA, 1);
                            if (sp < STASH) stashA[sp] = make_int2(t, v);
                        }
                    }
                }
            }
        }
        __syncthreads();
        int fc = flushCnt;
        for (int j = t; j < fc * 4; j += 256) {
            int gd = flushList[j >> 2];
            int lane4 = j & 3;
            int bb = gd >> 2, L = gd & 3;
            int4 v = *(int4*)&buf[bb][L * 16 + lane4 * 4];
            *(int4*)&stagingA[(size_t)bb * CAP1 + myBase[bb] + L * 16 + lane4 * 4] = v;
        }
        __syncthreads();
        if (t < NB) {
            int n = min(cur[t], BDEPTH);
            int lines = n >> 4, rem = n & 15;
            if (lines) for (int i = 0; i < rem; ++i) buf[t][i] = buf[t][lines * 16 + i];
            cur[t] = rem;
        }
        if (t == 0) flushCnt = 0;
        __syncthreads();
    }
}

// ---- binB: row-side radix (2-byte payload r&511) for degree counting.
// Same zero-per-edge-atomic machinery; replaces the 3.2M deg atomics.
__global__ __launch_bounds__(256) void binB_kernel(
        const int* __restrict__ row,
        int* __restrict__ gcurB, int* __restrict__ scurB,
        int2* __restrict__ stashB, unsigned short* __restrict__ stagingB) {
    __shared__ __align__(16) unsigned short buf[NB][BDEPTHB];   // 25 KB
    __shared__ int cur[NB];
    __shared__ int myBase[NB];
    __shared__ short flushList[2 * NB];
    __shared__ int flushCnt;
    int t = threadIdx.x;
    for (int i = t; i < NB; i += 256) cur[i] = 0;
    if (t == 0) flushCnt = 0;
    __syncthreads();
    int e0 = blockIdx.x * CHUNK;
    for (int batch = 0; batch <= NBATCH; ++batch) {
        if (batch < NBATCH) {
#pragma unroll
            for (int u = 0; u < 2; ++u) {
                int e = e0 + batch * BATCH + u * 256 + t;
                if (e < e0 + CHUNK) {
                    int r = row[e];
                    int bb = r >> 9;
                    unsigned short payload = (unsigned short)(r & 511);
                    int pos = atomicAdd(&cur[bb], 1);
                    if (pos < BDEPTHB) buf[bb][pos] = payload;
                    else { int sp = atomicAdd(scurB, 1);
                           if (sp < STASH) stashB[sp] = make_int2(bb, (int)payload); }
                }
            }
        } else {
            if (t < NB) {
                int rem = min(cur[t], BDEPTHB);
                if (rem & 31) {
                    int up = (rem + 31) & ~31;
                    for (int i = rem; i < up; ++i) buf[t][i] = 0xFFFF;
                    cur[t] = up;
                } else cur[t] = rem;
            }
        }
        __syncthreads();
        if (t < NB) {
            int n = min(cur[t], BDEPTHB);
            int lines = n >> 5;
            if (lines) {
                int base = atomicAdd(&gcurB[t], lines * 32);
                if (base + lines * 32 <= CAPB1) {
                    myBase[t] = base;
                    int li = atomicAdd(&flushCnt, lines);
                    for (int L = 0; L < lines; ++L)
                        flushList[li + L] = (short)((t << 2) | L);
                } else {
                    for (int i = 0; i < lines * 32; ++i) {
                        unsigned short v = buf[t][i];
                        if (v != 0xFFFF) {
                            int sp = atomicAdd(scurB, 1);
                            if (sp < STASH) stashB[sp] = make_int2(t, (int)v);
                        }
                    }
                }
            }
        }
        __syncthreads();
        int fc = flushCnt;
        for (int j = t; j < fc * 4; j += 256) {
            int gd = flushList[j >> 2];
            int lane4 = j & 3;
            int bb = gd >> 2, L = gd & 3;
            int4 v = *(int4*)&buf[bb][L * 32 + lane4 * 8];
            *(int4*)&stagingB[(size_t)bb * CAPB1 + myBase[bb] + L * 32 + lane4 * 8] = v;
        }
        __syncthreads();
        if (t < NB) {
            int n = min(cur[t], BDEPTHB);
            int lines = n >> 5, rem = n & 31;
            if (lines) for (int i = 0; i < rem; ++i) buf[t][i] = buf[t][lines * 32 + i];
            cur[t] = rem;
        }
        if (t == 0) flushCnt = 0;
        __syncthreads();
    }
}

// ---- degC: per row-bucket 512-counter LDS histogram -> dis directly -----
__global__ __launch_bounds__(256) void degC_kernel(
        const unsigned short* __restrict__ stagingB, const int* __restrict__ gcurB,
        const int* __restrict__ scurB, const int2* __restrict__ stashB,
        float* __restrict__ dis) {
    __shared__ int cnt512[512];
    int b = blockIdx.x, t = threadIdx.x;
    for (int i = t; i < 512; i += 256) cnt512[i] = 0;
    __syncthreads();
    const unsigned short* sb = stagingB + (size_t)b * CAPB1;
    int n = min(gcurB[b], CAPB1);
    for (int k = t; k < n; k += 256) {
        unsigned short p = sb[k];
        if (p != 0xFFFF) atomicAdd(&cnt512[p], 1);
    }
    int ns = min(*scurB, STASH);
    for (int k = t; k < ns; k += 256) {
        int2 se = stashB[k];
        if (se.x == b) atomicAdd(&cnt512[se.y], 1);
    }
    __syncthreads();
    for (int i = t; i < 512; i += 256) {
        int node = b * 512 + i;
        if (node < N_NODES) dis[node] = rsqrtf((float)(cnt512[i] + 1));  // +1 self loop
    }
}

// ---- csr2: per col-bucket, sort ~16-20K entries fully in LDS (512-counter
// histogram -> scan -> LDS scatter), stream rows_sorted out COALESCED into
// a fixed-stride window b*CAPR (no global scan, no scattered global writes).
__global__ __launch_bounds__(256) void csr2_kernel(
        const int* __restrict__ stagingA, const int* __restrict__ gcurA,
        const int* __restrict__ scurA, const int2* __restrict__ stashA,
        int* __restrict__ start, int* __restrict__ cnt,
        int* __restrict__ rows_sorted) {
    __shared__ int ebuf[CAPR];
    __shared__ int cnt512[512], off512[512], cur512[512];
    __shared__ int psum[256];
    int b = blockIdx.x, t = threadIdx.x;
    for (int i = t; i < 512; i += 256) { cnt512[i] = 0; cur512[i] = 0; }
    __syncthreads();
    const int* sb = stagingA + (size_t)b * CAP1;
    int n1 = min(gcurA[b], CAP1);
    for (int k = t; k < n1; k += 256) {
        int e = sb[k];
        if (e != -1) atomicAdd(&cnt512[(e >> 17) & 511], 1);
    }
    int ns = min(*scurA, STASH);
    for (int k = t; k < ns; k += 256) {
        int2 se = stashA[k];
        if (se.x == b && se.y != -1) atomicAdd(&cnt512[(se.y >> 17) & 511], 1);
    }
    __syncthreads();
    int a0 = cnt512[2 * t], a1 = cnt512[2 * t + 1];
    int ps = a0 + a1;
    psum[t] = ps;
    __syncthreads();
    for (int off = 1; off < 256; off <<= 1) {
        int v = (t >= off) ? psum[t - off] : 0;
        __syncthreads();
        psum[t] += v;
        __syncthreads();
    }
    int excl = psum[t] - ps;
    off512[2 * t] = excl;
    off512[2 * t + 1] = excl + a0;
    __syncthreads();
    for (int i = t; i < 512; i += 256) {
        int node = b * 512 + i;                    // max 100351 < 102400 (array pad)
        start[node] = b * CAPR + off512[i];
        int room = CAPR - off512[i];
        cnt[node]   = min(cnt512[i], max(room, 0));   // defensive clamp
    }
    for (int k = t; k < n1; k += 256) {
        int e = sb[k];
        if (e != -1) {
            int i = (e >> 17) & 511;
            int pos = atomicAdd(&cur512[i], 1);
            int dst = off512[i] + pos;
            if (dst < CAPR) ebuf[dst] = e & 0x1FFFF;
        }
    }
    for (int k = t; k < ns; k += 256) {
        int2 se = stashA[k];
        if (se.x == b && se.y != -1) {
            int i = (se.y >> 17) & 511;
            int pos = atomicAdd(&cur512[i], 1);
            int dst = off512[i] + pos;
            if (dst < CAPR) ebuf[dst] = se.y & 0x1FFFF;
        }
    }
    __syncthreads();
    int total = min(off512[511] + cnt512[511], CAPR);
    int* outp = rows_sorted + (size_t)b * CAPR;
    for (int k = t; k < total; k += 256) outp[k] = ebuf[k];   // coalesced
}

// ------- layer-1 aggregation (dis-folded) + relu + row-sum s -------------
__global__ void agg1_kernel(const int* __restrict__ rows_sorted,
                            const int* __restrict__ start, const int* __restrict__ cnt,
                            const float* __restrict__ dis, const float* __restrict__ h1t,
                            float* __restrict__ g, float* __restrict__ s_out) {
    int idx = blockIdx.x * blockDim.x + threadIdx.x;
    if (idx >= N_NODES * 4) return;
    int c = idx >> 2;
    int q = idx & 3;
    float dc = dis[c];
    const float4* h4 = (const float4*)h1t;
    float4 acc = h4[(size_t)c * 4 + q];
    float ss = dc;
    int k0 = start[c];
    int k1 = k0 + cnt[c];
    for (int k = k0; k < k1; ++k) {
        int r = rows_sorted[k];
        float4 v = h4[(size_t)r * 4 + q];
        acc.x += v.x; acc.y += v.y; acc.z += v.z; acc.w += v.w;
        if (q == 0) ss += dis[r];
    }
    acc.x = dc * fmaxf(acc.x * dc, 0.0f);
    acc.y = dc * fmaxf(acc.y * dc, 0.0f);
    acc.z = dc * fmaxf(acc.z * dc, 0.0f);
    acc.w = dc * fmaxf(acc.w * dc, 0.0f);
    ((float4*)g)[(size_t)c * 4 + q] = acc;
    if (q == 0) s_out[c] = dc * ss;
}

// ---------------- layer-2 aggregation (dis-folded): t = A_hat g ----------
__global__ void agg2_kernel(const int* __restrict__ rows_sorted,
                            const int* __restrict__ start, const int* __restrict__ cnt,
                            const float* __restrict__ dis, const float* __restrict__ g,
                            float* __restrict__ t) {
    int idx = blockIdx.x * blockDim.x + threadIdx.x;
    if (idx >= N_NODES * 4) return;
    int c = idx >> 2;
    int q = idx & 3;
    float dc = dis[c];
    const float4* h4 = (const float4*)g;
    float4 acc = h4[(size_t)c * 4 + q];
    int k0 = start[c];
    int k1 = k0 + cnt[c];
    for (int k = k0; k < k1; ++k) {
        int r = rows_sorted[k];
        float4 v = h4[(size_t)r * 4 + q];
        acc.x += v.x; acc.y += v.y; acc.z += v.z; acc.w += v.w;
    }
    acc.x *= dc; acc.y *= dc; acc.z *= dc; acc.w *= dc;
    ((float4*)t)[(size_t)c * 4 + q] = acc;
}

// ------- fused: out = log_softmax(t @ W2 + s*b2^T), wave per node ---------
__global__ void mm2lsm_kernel(const float* __restrict__ t, const float* __restrict__ s,
                              const float* __restrict__ W2, const float* __restrict__ b2,
                              float* __restrict__ out) {
    __shared__ float w2s[F1 * F2];
    __shared__ float b2s[F2];
    __shared__ float ts[4 * F1];
    int tid = threadIdx.x;
    for (int i = tid; i < F1 * F2; i += 256) w2s[i] = W2[i];
    if (tid < F2) b2s[tid] = b2[tid];
    int nodeBase = blockIdx.x * 4;
    if (tid < 4 * F1) ts[tid] = t[(size_t)nodeBase * F1 + tid];
    __syncthreads();
    int w    = tid >> 6;
    int lane = tid & 63;
    int c = nodeBase + w;
    float sc = s[c];
    float v = -INFINITY;
    if (lane < F2) {
        float acc = sc * b2s[lane];
#pragma unroll
        for (int k = 0; k < F1; ++k)
            acc = fmaf(ts[w * F1 + k], w2s[k * F2 + lane], acc);
        v = acc;
    }
    float m = v;
#pragma unroll
    for (int off = 32; off; off >>= 1)
        m = fmaxf(m, __shfl_xor(m, off, 64));
    float ex = (lane < F2) ? expf(v - m) : 0.0f;
    float ssum = ex;
#pragma unroll
    for (int off = 32; off; off >>= 1)
        ssum += __shfl_xor(ssum, off, 64);
    if (lane < F2) out[(size_t)c * F2 + lane] = v - m - logf(ssum);
}

extern "C" void kernel_launch(void* const* d_in, const int* in_sizes, int n_in,
                              void* d_out, int out_size, void* d_ws, size_t ws_size,
                              hipStream_t stream) {
    const float* x   = (const float*)d_in[0];
    const int*   ei  = (const int*)d_in[1];
    const float* W1  = (const float*)d_in[2];
    const float* b1  = (const float*)d_in[3];
    const float* W2  = (const float*)d_in[4];
    const float* b2  = (const float*)d_in[5];
    float* out = (float*)d_out;

    const int* row = ei;             // edge_index[0]
    const int* col = ei + N_EDGES;   // edge_index[1]

    // workspace layout (4B words), P = 102400; total ~8.48M words = 33.9 MB
    const size_t P = 102400;
    float* fws = (float*)d_ws;
    float* dis = fws;                                  // P
    float* s   = dis + P;                              // P
    int* start = (int*)(s + P);                        // P
    int* cnt   = start + P;                            // P
    int* gcurA = cnt + P;                              // 256
    int* gcurB = gcurA + 256;                          // 256
    int* scurA = gcurB + 256;                          // 64 (1 used)
    int* scurB = scurA + 64;                           // 64
    int2* stashA = (int2*)(scurB + 64);                // 2*STASH words
    int2* stashB = stashA + STASH;                     // 2*STASH words
    int* rows_sorted = (int*)(stashB + STASH);         // 196*CAPR = 3,462,144 words
    // stagingB (196*CAPB1 ushorts = 2,922,752 words) aliases rows_sorted:
    // degC (reads stagingB) runs BEFORE csr2 (writes rows_sorted).
    unsigned short* stagingB = (unsigned short*)rows_sorted;
    int* stagingA = rows_sorted + (size_t)NB * CAPR;   // 196*CAP1 = 4,587,968 words
    // stagingA dead after csr2; h1t (16P) + g (16P) alias it (32P <= 4.59M OK).
    // t aliases h1t (h1t dead after agg1, t written in agg2).
    float* h1t = (float*)stagingA;
    float* g   = (float*)stagingA + 16 * P;
    float* t   = (float*)stagingA;

    const int B = 256;

    // ---- graph build: zero-per-edge-atomic radix + local histograms ----
    init_kernel<<<1, B, 0, stream>>>(gcurA, gcurB, scurA, scurB);
    binA_kernel<<<NWGA, B, 0, stream>>>(row, col, gcurA, scurA, stashA, stagingA);
    binB_kernel<<<NWGA, B, 0, stream>>>(row, gcurB, scurB, stashB, stagingB);
    degC_kernel<<<NB, B, 0, stream>>>(stagingB, gcurB, scurB, stashB, dis);
    csr2_kernel<<<NB, B, 0, stream>>>(stagingA, gcurA, scurA, stashA,
                                      start, cnt, rows_sorted);

    // ---- layer 1: h1t = dis*(x@W1+b1) ; g~ = dis*relu(dis*A-sum) --------
    mm1_kernel<<<(N_NODES + BR - 1) / BR, B, 0, stream>>>(x, W1, b1, dis, h1t);
    agg1_kernel<<<(N_NODES * 4 + B - 1) / B, B, 0, stream>>>(
        rows_sorted, start, cnt, dis, h1t, g, s);

    // ---- layer 2 (W2 commuted past aggregation): t = A_hat g~ -----------
    agg2_kernel<<<(N_NODES * 4 + B - 1) / B, B, 0, stream>>>(
        rows_sorted, start, cnt, dis, g, t);

    // ---- out = log_softmax(t@W2 + s*b2) ----
    mm2lsm_kernel<<<N_NODES / 4, B, 0, stream>>>(t, s, W2, b2, out);
}